// Round 12
// baseline (932.448 us; speedup 1.0000x reference)
//
#include <hip/hip_runtime.h>
#include <hip/hip_bf16.h>

#define BB 2
#define LL 2048
#define DD 1024
#define HH 16
#define DK 64
#define UU 40
#define BH (BB*HH)

typedef unsigned short u16;
typedef float f32x4 __attribute__((ext_vector_type(4)));
typedef short s16x8 __attribute__((ext_vector_type(8)));

__device__ inline float b2f_r8(u16 x) {
    union { unsigned short u; __hip_bfloat16 b; } c; c.u = x;
    return __bfloat162float(c.b);
}
__device__ inline float ldf_r8(const void* p, size_t i, int isF) {
    return isF ? ((const float*)p)[i] : b2f_r8(((const u16*)p)[i]);
}
__device__ inline f32x4 ld4_r8(const void* p, size_t i, int isF) {
    if (isF) return *(const f32x4*)((const float*)p + i);
    ushort4 v = *(const ushort4*)((const u16*)p + i);
    f32x4 r;
    r[0] = b2f_r8(v.x); r[1] = b2f_r8(v.y); r[2] = b2f_r8(v.z); r[3] = b2f_r8(v.w);
    return r;
}
__device__ inline void cvt2_r8(float x, u16& h, u16& l) {
    union { __hip_bfloat16 b; u16 u; } ch, cl;
    ch.b = __float2bfloat16(x);
    float hf = __bfloat162float(ch.b);
    cl.b = __float2bfloat16(x - hf);
    h = ch.u; l = cl.u;
}

// ---------------- K0: input dtype probe (+ zero the ambig counter) ----------------
__global__ __launch_bounds__(256) void detect_dtype_r17(const u16* __restrict__ q,
                                                        int* __restrict__ flag,
                                                        int* __restrict__ cnt) {
    __shared__ float red[256];
    int tid = threadIdx.x;
    float mx = 0.f;
    for (int i = tid; i < 4096; i += 256) {
        float v = fabsf(b2f_r8(q[i]));
        if (!(v < 1e30f)) v = 1e38f;
        mx = fmaxf(mx, v);
    }
    red[tid] = mx; __syncthreads();
    for (int s = 128; s > 0; s >>= 1) {
        if (tid < s) red[tid] = fmaxf(red[tid], red[tid + s]);
        __syncthreads();
    }
    if (tid == 0) { *flag = (red[0] > 1e20f) ? 1 : 0; *cnt = 0; }
}

#define PAD 132

// ---- K1: fp32 projection K (z=0) / Q (z=1) (unchanged — proven r13). ----
__global__ __launch_bounds__(256) void proj_f4_r13(
    const void* __restrict__ key, const void* __restrict__ query,
    const void* __restrict__ Wk, const void* __restrict__ Wq,
    const void* __restrict__ bk, const void* __restrict__ bq,
    float* __restrict__ Kf, float* __restrict__ Qf,
    const int* __restrict__ flag)
{
    __shared__ float sX[32 * PAD];   // [d][n-row], 128 rows
    __shared__ float sW[32 * 68];    // [d][f-col], 64 cols
    int tid = threadIdx.x;
    int n0 = blockIdx.x * 128, f0 = blockIdx.y * 64, z = blockIdx.z;
    const void* X    = z ? query : key;
    const void* W    = z ? Wq    : Wk;
    const void* bias = z ? bq    : bk;
    float* out       = z ? Qf    : Kf;
    int isF = *flag;
    int tx = tid & 15, ty = tid >> 4;

    float acc[8][4];
#pragma unroll
    for (int a = 0; a < 8; ++a)
#pragma unroll
        for (int c = 0; c < 4; ++c) acc[a][c] = 0.f;

    for (int kc = 0; kc < 32; ++kc) {
        __syncthreads();
#pragma unroll
        for (int it = 0; it < 4; ++it) {
            int row = 64 * (it & 1) + (tid >> 2);
            int d4 = (tid & 3) | ((it >> 1) << 2);
            f32x4 v = ld4_r8(X, (size_t)(n0 + row) * DD + kc * 32 + d4 * 4, isF);
#pragma unroll
            for (int cc = 0; cc < 4; ++cc)
                sX[(4 * d4 + cc) * PAD + row] = v[cc];
        }
#pragma unroll
        for (int it = 0; it < 2; ++it) {
            int row = tid >> 2;
            int d4 = (tid & 3) | (it << 2);
            f32x4 v = ld4_r8(W, (size_t)(f0 + row) * DD + kc * 32 + d4 * 4, isF);
#pragma unroll
            for (int cc = 0; cc < 4; ++cc)
                sW[(4 * d4 + cc) * 68 + row] = v[cc];
        }
        __syncthreads();
        for (int d = 0; d < 32; ++d) {
            const f32x4 xa = *(const f32x4*)(&sX[d * PAD + ty * 4]);
            const f32x4 xb = *(const f32x4*)(&sX[d * PAD + 64 + ty * 4]);
            const f32x4 wa = *(const f32x4*)(&sW[d * 68 + tx * 4]);
            float xv[8] = {xa[0], xa[1], xa[2], xa[3], xb[0], xb[1], xb[2], xb[3]};
#pragma unroll
            for (int a = 0; a < 8; ++a)
#pragma unroll
                for (int c = 0; c < 4; ++c)
                    acc[a][c] = fmaf(xv[a], wa[c], acc[a][c]);
        }
    }
#pragma unroll
    for (int a = 0; a < 8; ++a) {
        int n = n0 + (a >> 2) * 64 + ty * 4 + (a & 3);
        int b = n >> 11, l = n & (LL - 1);
#pragma unroll
        for (int c = 0; c < 4; ++c) {
            int f = f0 + tx * 4 + c;
            int h = f >> 6, dk = f & 63;
            out[((size_t)(b * HH + h) * LL + l) * DK + dk] =
                acc[a][c] + ldf_r8(bias, (size_t)f, isF);
        }
    }
}

// ---- K1a: pre-convert Wv to bf16 hi/lo (unchanged). ----
__global__ __launch_bounds__(256) void preconvW_r16(
    const void* __restrict__ Wv, u16* __restrict__ Whi, u16* __restrict__ Wlo,
    const int* __restrict__ flag)
{
    int isF = *flag;
    size_t i = ((size_t)blockIdx.x * 256 + threadIdx.x) * 4;
    f32x4 v = ld4_r8(Wv, i, isF);
    ushort4 h4, l4;
    cvt2_r8(v[0], h4.x, l4.x);
    cvt2_r8(v[1], h4.y, l4.y);
    cvt2_r8(v[2], h4.z, l4.z);
    cvt2_r8(v[3], h4.w, l4.w);
    *(ushort4*)&Whi[i] = h4;
    *(ushort4*)&Wlo[i] = l4;
}

// ---- K1b: V projection via bf16x3 MFMA (unchanged — proven r16). ----
#define LDK 72
__global__ __launch_bounds__(256) void proj_mfma_v_r16(
    const void* __restrict__ X, const u16* __restrict__ Whi,
    const u16* __restrict__ Wlo, const void* __restrict__ bias,
    float* __restrict__ out, const int* __restrict__ flag)
{
    __shared__ u16 Ahi[64 * LDK];
    __shared__ u16 Alo[64 * LDK];
    __shared__ u16 Bhi[128 * LDK];
    __shared__ u16 Blo[128 * LDK];
    int tid = threadIdx.x;
    int n0 = blockIdx.x * 64, f0 = blockIdx.y * 128;
    int isF = *flag;
    int lane = tid & 63, w = tid >> 6, wr = w >> 1, wc = w & 1;

    f32x4 acc[2][4] = {};

    for (int kc = 0; kc < 16; ++kc) {
        __syncthreads();
#pragma unroll
        for (int it = 0; it < 4; ++it) {
            int i = it * 256 + tid;
            int row = i >> 4, c = (i & 15) << 2;
            f32x4 v = ld4_r8(X, (size_t)(n0 + row) * DD + kc * 64 + c, isF);
            ushort4 h4, l4;
            cvt2_r8(v[0], h4.x, l4.x);
            cvt2_r8(v[1], h4.y, l4.y);
            cvt2_r8(v[2], h4.z, l4.z);
            cvt2_r8(v[3], h4.w, l4.w);
            *(ushort4*)&Ahi[row * LDK + c] = h4;
            *(ushort4*)&Alo[row * LDK + c] = l4;
        }
#pragma unroll
        for (int it = 0; it < 8; ++it) {
            int i = it * 256 + tid;
            int row = i >> 4, c = (i & 15) << 2;
            size_t go = (size_t)(f0 + row) * DD + kc * 64 + c;
            *(ushort4*)&Bhi[row * LDK + c] = *(const ushort4*)&Whi[go];
            *(ushort4*)&Blo[row * LDK + c] = *(const ushort4*)&Wlo[go];
        }
        __syncthreads();
#pragma unroll
        for (int kk = 0; kk < 2; ++kk) {
            int koff = kk * 32 + (lane >> 4) * 8;
            s16x8 ah[2], al[2];
#pragma unroll
            for (int mi = 0; mi < 2; ++mi) {
                int r = wr * 32 + mi * 16 + (lane & 15);
                ah[mi] = *(const s16x8*)&Ahi[r * LDK + koff];
                al[mi] = *(const s16x8*)&Alo[r * LDK + koff];
            }
#pragma unroll
            for (int ni = 0; ni < 4; ++ni) {
                int r = wc * 64 + ni * 16 + (lane & 15);
                s16x8 bh = *(const s16x8*)&Bhi[r * LDK + koff];
                s16x8 bl = *(const s16x8*)&Blo[r * LDK + koff];
#pragma unroll
                for (int mi = 0; mi < 2; ++mi) {
                    acc[mi][ni] = __builtin_amdgcn_mfma_f32_16x16x32_bf16(ah[mi], bh, acc[mi][ni], 0, 0, 0);
                    acc[mi][ni] = __builtin_amdgcn_mfma_f32_16x16x32_bf16(al[mi], bh, acc[mi][ni], 0, 0, 0);
                    acc[mi][ni] = __builtin_amdgcn_mfma_f32_16x16x32_bf16(ah[mi], bl, acc[mi][ni], 0, 0, 0);
                }
            }
        }
    }

#pragma unroll
    for (int ni = 0; ni < 4; ++ni) {
        int f = f0 + wc * 64 + ni * 16 + (lane & 15);
        float bb = ldf_r8(bias, (size_t)f, isF);
        int h = f >> 6, dk = f & 63;
#pragma unroll
        for (int mi = 0; mi < 2; ++mi) {
            int nbase = n0 + wr * 32 + mi * 16 + ((lane >> 4) << 2);
#pragma unroll
            for (int j2 = 0; j2 < 4; ++j2) {
                int n = nbase + j2, b = n >> 11, l = n & (LL - 1);
                out[((size_t)(b * HH + h) * LL + l) * DK + dk] = acc[mi][ni][j2] + bb;
            }
        }
    }
}

// ---------------- K2b: Kbar (unchanged) ----------------
__global__ __launch_bounds__(256) void kbar_r8(
    const float* __restrict__ Kf, double* __restrict__ Kbar)
{
    __shared__ double red[256];
    int bh = blockIdx.x, tid = threadIdx.x;
    int d = tid & 63, seg = tid >> 6;
    double s = 0;
    for (int l = seg * 512; l < seg * 512 + 512; ++l)
        s += (double)Kf[((size_t)bh * LL + l) * DK + d];
    red[tid] = s; __syncthreads();
    if (tid < 128) red[tid] += red[tid + 128];
    __syncthreads();
    if (tid < 64) Kbar[(size_t)bh * DK + d] = (red[tid] + red[tid + 64]) * (1.0 / (double)LL);
}

// ---- K3a: approx rowmax top-2 via bf16x3 MFMA. A=K (D-row = k), B=Q
// (D-col = q). Per block: 128 q x all 2048 k. Outputs per row: approx
// top-2 values + argmax index. Operand layout cloned from proven proj_mfma.
__global__ __launch_bounds__(256) void statsq_r17(
    const float* __restrict__ Qf, const float* __restrict__ Kf,
    float* __restrict__ M1, int* __restrict__ I1, float* __restrict__ M2)
{
    __shared__ u16 Qhi[128 * LDK];
    __shared__ u16 Qlo[128 * LDK];
    __shared__ u16 Khi[128 * LDK];
    __shared__ u16 Klo[128 * LDK];
    int tid = threadIdx.x;
    int q0 = blockIdx.x * 128, bh = blockIdx.y;
    int lane = tid & 63, w = tid >> 6;
    int qw = w * 32;     // each wave owns 32 q-rows, all k

    // stage + convert Q tile once (128 rows x 64 d)
#pragma unroll
    for (int it = 0; it < 8; ++it) {
        int i = it * 256 + tid;
        int row = i >> 4, c = (i & 15) << 2;
        f32x4 v = *(const f32x4*)&Qf[((size_t)bh * LL + q0 + row) * DK + c];
        ushort4 h4, l4;
        cvt2_r8(v[0], h4.x, l4.x);
        cvt2_r8(v[1], h4.y, l4.y);
        cvt2_r8(v[2], h4.z, l4.z);
        cvt2_r8(v[3], h4.w, l4.w);
        *(ushort4*)&Qhi[row * LDK + c] = h4;
        *(ushort4*)&Qlo[row * LDK + c] = l4;
    }
    __syncthreads();
    // B-fragments (Q) to regs: [qi][kk]
    s16x8 Bh[2][2], Bl[2][2];
#pragma unroll
    for (int qi = 0; qi < 2; ++qi)
#pragma unroll
        for (int kk = 0; kk < 2; ++kk) {
            int r = qw + qi * 16 + (lane & 15);
            int koff = kk * 32 + (lane >> 4) * 8;
            Bh[qi][kk] = *(const s16x8*)&Qhi[r * LDK + koff];
            Bl[qi][kk] = *(const s16x8*)&Qlo[r * LDK + koff];
        }

    float m1[2] = {-1e30f, -1e30f}, m2[2] = {-1e30f, -1e30f};
    int i1[2] = {0, 0};

    for (int kt = 0; kt < 16; ++kt) {
        __syncthreads();
        int kbase = kt * 128;
#pragma unroll
        for (int it = 0; it < 8; ++it) {
            int i = it * 256 + tid;
            int row = i >> 4, c = (i & 15) << 2;
            f32x4 v = *(const f32x4*)&Kf[((size_t)bh * LL + kbase + row) * DK + c];
            ushort4 h4, l4;
            cvt2_r8(v[0], h4.x, l4.x);
            cvt2_r8(v[1], h4.y, l4.y);
            cvt2_r8(v[2], h4.z, l4.z);
            cvt2_r8(v[3], h4.w, l4.w);
            *(ushort4*)&Khi[row * LDK + c] = h4;
            *(ushort4*)&Klo[row * LDK + c] = l4;
        }
        __syncthreads();
#pragma unroll
        for (int ki = 0; ki < 8; ++ki) {
#pragma unroll
            for (int qi = 0; qi < 2; ++qi) {
                f32x4 acc = {0.f, 0.f, 0.f, 0.f};
#pragma unroll
                for (int kk = 0; kk < 2; ++kk) {
                    int koff = kk * 32 + (lane >> 4) * 8;
                    int r = ki * 16 + (lane & 15);
                    s16x8 Ah = *(const s16x8*)&Khi[r * LDK + koff];
                    s16x8 Al = *(const s16x8*)&Klo[r * LDK + koff];
                    acc = __builtin_amdgcn_mfma_f32_16x16x32_bf16(Ah, Bh[qi][kk], acc, 0, 0, 0);
                    acc = __builtin_amdgcn_mfma_f32_16x16x32_bf16(Al, Bh[qi][kk], acc, 0, 0, 0);
                    acc = __builtin_amdgcn_mfma_f32_16x16x32_bf16(Ah, Bl[qi][kk], acc, 0, 0, 0);
                }
#pragma unroll
                for (int j = 0; j < 4; ++j) {
                    float val = acc[j];
                    int kg = kbase + ki * 16 + ((lane >> 4) << 2) + j;
                    bool g1 = val > m1[qi];
                    bool g2 = val > m2[qi];
                    m2[qi] = g1 ? m1[qi] : (g2 ? val : m2[qi]);
                    i1[qi] = g1 ? kg : i1[qi];
                    m1[qi] = g1 ? val : m1[qi];
                }
            }
        }
    }
    // merge across lanes sharing the same q (xor 16, 32)
#pragma unroll
    for (int qi = 0; qi < 2; ++qi) {
#pragma unroll
        for (int off = 16; off <= 32; off <<= 1) {
            float ov1 = __shfl_xor(m1[qi], off);
            int oi1 = __shfl_xor(i1[qi], off);
            float ov2 = __shfl_xor(m2[qi], off);
            if (ov1 > m1[qi]) {
                m2[qi] = fmaxf(m1[qi], ov2);
                m1[qi] = ov1; i1[qi] = oi1;
            } else {
                m2[qi] = fmaxf(m2[qi], fmaxf(ov1, ov2) == ov1 ? ov1 : ov2);
                m2[qi] = fmaxf(m2[qi], ov1);   // ov2 <= ov1 here; keep simple+safe
            }
        }
    }
    if ((lane >> 4) == 0) {
#pragma unroll
        for (int qi = 0; qi < 2; ++qi) {
            int q = q0 + qw + qi * 16 + (lane & 15);
            size_t o = (size_t)bh * LL + q;
            M1[o] = m1[qi]; I1[o] = i1[qi]; M2[o] = m2[qi];
        }
    }
}

// ---- K3b: exact rescue. Per row: exact-chain S[i1] (bit-identical fp32
// chain) + fp64 Q.Kbar -> Mv. Ambiguous rows (approx gap <= GAPTHR) listed.
#define GAPTHR 0.02f
__global__ __launch_bounds__(256) void rescue_r17(
    const float* __restrict__ Qf, const float* __restrict__ Kf,
    const double* __restrict__ Kbar, const float* __restrict__ M1,
    const int* __restrict__ I1, const float* __restrict__ M2,
    double* __restrict__ Mv, int* __restrict__ alist, int* __restrict__ cnt)
{
    int gid = blockIdx.x * 256 + threadIdx.x;   // 65536 rows
    int bh = gid >> 11, q = gid & (LL - 1);
    const float* qp = Qf + ((size_t)bh * LL + q) * DK;
    const float* kp = Kf + ((size_t)bh * LL + I1[gid]) * DK;
    float s = 0.f;
    for (int d4 = 0; d4 < 16; ++d4) {
        const f32x4 qv = *(const f32x4*)(qp + d4 * 4);
        const f32x4 kv = *(const f32x4*)(kp + d4 * 4);
        s = fmaf(qv[0], kv[0], s);
        s = fmaf(qv[1], kv[1], s);
        s = fmaf(qv[2], kv[2], s);
        s = fmaf(qv[3], kv[3], s);
    }
    const double* kb = Kbar + (size_t)bh * DK;
    double md = 0;
    for (int d = 0; d < DK; ++d) md += (double)qp[d] * kb[d];
    Mv[gid] = (double)s - md;
    if (!(M1[gid] - M2[gid] > GAPTHR)) {
        int slot = atomicAdd(cnt, 1);
        alist[slot] = gid;
    }
}

// ---- K3c: ambiguous rows — full exact rescan, one wave per row. ----
__global__ __launch_bounds__(256) void ambig_r17(
    const float* __restrict__ Qf, const float* __restrict__ Kf,
    const double* __restrict__ Kbar, const int* __restrict__ alist,
    const int* __restrict__ cnt, double* __restrict__ Mv)
{
    int lane = threadIdx.x & 63;
    int wid = blockIdx.x * 4 + (threadIdx.x >> 6);
    int n = *cnt;
    for (int sIdx = wid; sIdx < n; sIdx += 512) {
        int gid = alist[sIdx];
        int bh = gid >> 11, q = gid & (LL - 1);
        const float* qp = Qf + ((size_t)bh * LL + q) * DK;
        f32x4 qr[16];
#pragma unroll
        for (int d4 = 0; d4 < 16; ++d4) qr[d4] = *(const f32x4*)(qp + d4 * 4);
        float mx = -1e30f;
        for (int t = 0; t < 32; ++t) {
            int k = t * 64 + lane;
            const float* kp = Kf + ((size_t)bh * LL + k) * DK;
            float s = 0.f;
#pragma unroll
            for (int d4 = 0; d4 < 16; ++d4) {
                const f32x4 kv = *(const f32x4*)(kp + d4 * 4);
                s = fmaf(qr[d4][0], kv[0], s);
                s = fmaf(qr[d4][1], kv[1], s);
                s = fmaf(qr[d4][2], kv[2], s);
                s = fmaf(qr[d4][3], kv[3], s);
            }
            mx = fmaxf(mx, s);
        }
#pragma unroll
        for (int off = 1; off < 64; off <<= 1)
            mx = fmaxf(mx, __shfl_xor(mx, off));
        if (lane == 0) {
            const double* kb = Kbar + (size_t)bh * DK;
            double md = 0;
            for (int d = 0; d < DK; ++d) md += (double)qp[d] * kb[d];
            Mv[gid] = (double)mx - md;
        }
    }
}

// ------- K4: exact top-40, one wave per bh (unchanged — proven). -------
__global__ __launch_bounds__(64) void topk_wave_r10(
    const double* __restrict__ Mv, int* __restrict__ sel)
{
    int bh = blockIdx.x, lane = threadIdx.x;
    double v[32];
#pragma unroll
    for (int t = 0; t < 32; ++t) v[t] = Mv[(size_t)bh * LL + t * 64 + lane];
    for (int u = 0; u < UU; ++u) {
        double bv = -1e301; int bi = LL;
#pragma unroll
        for (int t = 0; t < 32; ++t) {
            double x = v[t]; int j = t * 64 + lane;
            if (x > bv || (x == bv && j < bi)) { bv = x; bi = j; }
        }
#pragma unroll
        for (int off = 1; off < 64; off <<= 1) {
            double ov = __shfl_xor(bv, off); int oi = __shfl_xor(bi, off);
            if (ov > bv || (ov == bv && oi < bi)) { bv = ov; bi = oi; }
        }
        if ((bi & 63) == lane) {
            int ts = bi >> 6;
#pragma unroll
            for (int t = 0; t < 32; ++t)
                if (t == ts) v[t] = -1e302;
        }
        if (lane == 0) sel[bh * UU + u] = bi;
    }
}

// ---- K5a: S[u][l] per (bh, 128-l chunk) (unchanged r15). ----
__global__ __launch_bounds__(256) void scores_r15(
    const float* __restrict__ Qf, const float* __restrict__ Kf,
    const int* __restrict__ sel, float* __restrict__ S)
{
    __shared__ float sK[128 * 68];
    __shared__ float qsm[40 * 68];
    __shared__ int qpos[UU];
    int lq = blockIdx.x, bh = blockIdx.y, tid = threadIdx.x;
    int l0 = lq * 128;
    if (tid < UU) qpos[tid] = sel[bh * UU + tid];
    __syncthreads();
    for (int i = tid; i < 640; i += 256) {
        int u = i >> 4, c4 = i & 15;
        *(f32x4*)&qsm[u * 68 + c4 * 4] =
            *(const f32x4*)&Qf[((size_t)bh * LL + qpos[u]) * DK + c4 * 4];
    }
#pragma unroll
    for (int it = 0; it < 8; ++it) {
        int idx = it * 256 + tid;
        int l = idx >> 4, d4 = idx & 15;
        *(f32x4*)&sK[l * 68 + d4 * 4] =
            *(const f32x4*)&Kf[((size_t)bh * LL + l0 + l) * DK + d4 * 4];
    }
    __syncthreads();
    int gu = tid >> 5, lt = tid & 31;
    float acc[5][4];
#pragma unroll
    for (int ui = 0; ui < 5; ++ui)
#pragma unroll
        for (int li = 0; li < 4; ++li) acc[ui][li] = 0.f;
    for (int d16 = 0; d16 < 16; ++d16) {
        f32x4 qf[5], kf[4];
#pragma unroll
        for (int ui = 0; ui < 5; ++ui)
            qf[ui] = *(const f32x4*)&qsm[(gu + 8 * ui) * 68 + d16 * 4];
#pragma unroll
        for (int li = 0; li < 4; ++li)
            kf[li] = *(const f32x4*)&sK[(lt + 32 * li) * 68 + d16 * 4];
#pragma unroll
        for (int ui = 0; ui < 5; ++ui)
#pragma unroll
            for (int li = 0; li < 4; ++li)
#pragma unroll
                for (int c = 0; c < 4; ++c)
                    acc[ui][li] = fmaf(qf[ui][c], kf[li][c], acc[ui][li]);
    }
#pragma unroll
    for (int ui = 0; ui < 5; ++ui) {
        int u = gu + 8 * ui;
        int qp = qpos[u];
#pragma unroll
        for (int li = 0; li < 4; ++li) {
            int l = l0 + lt + 32 * li;
            float s = acc[ui][li] * 0.125f;
            if (l > qp) s -= 1e9f;
            S[((size_t)bh * UU + u) * LL + l] = s;
        }
    }
}

// ---- K5b: row softmax -> probs (unchanged). ----
__global__ __launch_bounds__(256) void softmax_r12(
    const float* __restrict__ S, float* __restrict__ probsOut)
{
    __shared__ float red[256];
    int u = blockIdx.x, bh = blockIdx.y, tid = threadIdx.x;
    size_t rowo = ((size_t)bh * UU + u) * LL;
    float sloc[8];
    float lmax = -INFINITY;
#pragma unroll
    for (int c = 0; c < 8; ++c) {
        sloc[c] = S[rowo + c * 256 + tid];
        lmax = fmaxf(lmax, sloc[c]);
    }
    red[tid] = lmax; __syncthreads();
    for (int s2 = 128; s2 > 0; s2 >>= 1) {
        if (tid < s2) red[tid] = fmaxf(red[tid], red[tid + s2]);
        __syncthreads();
    }
    float mval = red[0];
    __syncthreads();
    float lsum = 0.f;
#pragma unroll
    for (int c = 0; c < 8; ++c) { sloc[c] = expf(sloc[c] - mval); lsum += sloc[c]; }
    red[tid] = lsum; __syncthreads();
    for (int s2 = 128; s2 > 0; s2 >>= 1) {
        if (tid < s2) red[tid] += red[tid + s2];
        __syncthreads();
    }
    float inv = 1.0f / red[0];
#pragma unroll
    for (int c = 0; c < 8; ++c)
        probsOut[rowo + c * 256 + tid] = sloc[c] * inv;
}

// ---- K5c: PV partials (unchanged r15). ----
__global__ __launch_bounds__(256) void pv_r15(
    const float* __restrict__ probsOut, const float* __restrict__ Vf,
    float* __restrict__ part)
{
    __shared__ float pP[20 * 256];
    int lq = blockIdx.x, bh = blockIdx.y, ug2 = blockIdx.z, tid = threadIdx.x;
    int l0 = lq * 256;
#pragma unroll
    for (int it = 0; it < 5; ++it) {
        int idx = it * 256 + tid;
        int ur = idx >> 6, l4 = idx & 63;
        *(f32x4*)&pP[ur * 256 + l4 * 4] =
            *(const f32x4*)&probsOut[((size_t)bh * UU + ug2 * 20 + ur) * LL + l0 + l4 * 4];
    }
    __syncthreads();
    int dk = tid & 63, ug = tid >> 6;
    const float* vb = Vf + ((size_t)bh * LL + l0) * DK + dk;
    float acc[5];
#pragma unroll
    for (int j = 0; j < 5; ++j) acc[j] = 0.f;
    for (int l4 = 0; l4 < 64; ++l4) {
        float vv0 = vb[(size_t)(l4 * 4 + 0) * DK];
        float vv1 = vb[(size_t)(l4 * 4 + 1) * DK];
        float vv2 = vb[(size_t)(l4 * 4 + 2) * DK];
        float vv3 = vb[(size_t)(l4 * 4 + 3) * DK];
#pragma unroll
        for (int j = 0; j < 5; ++j) {
            const f32x4 p4 = *(const f32x4*)&pP[(ug * 5 + j) * 256 + l4 * 4];
            acc[j] = fmaf(p4[0], vv0, acc[j]);
            acc[j] = fmaf(p4[1], vv1, acc[j]);
            acc[j] = fmaf(p4[2], vv2, acc[j]);
            acc[j] = fmaf(p4[3], vv3, acc[j]);
        }
    }
#pragma unroll
    for (int j = 0; j < 5; ++j) {
        int u = ug2 * 20 + ug * 5 + j;
        part[(((size_t)bh * 8 + lq) * UU + u) * DK + dk] = acc[j];
    }
}

// ---- K5d: reduce 8 chunk-partials -> attnOut (unchanged). ----
__global__ __launch_bounds__(64) void pvred_r12(
    const float* __restrict__ part, float* __restrict__ attnOut)
{
    int u = blockIdx.x, bh = blockIdx.y, dk = threadIdx.x;
    int b = bh >> 4, h = bh & 15;
    float s = 0.f;
#pragma unroll
    for (int lq = 0; lq < 8; ++lq)
        s += part[(((size_t)bh * 8 + lq) * UU + u) * DK + dk];
    attnOut[((size_t)b * UU + u) * DD + h * DK + dk] = s;
}

extern "C" void kernel_launch(void* const* d_in, const int* in_sizes, int n_in,
                              void* d_out, int out_size, void* d_ws, size_t ws_size,
                              hipStream_t stream) {
    (void)in_sizes; (void)n_in; (void)out_size; (void)ws_size;
    const void* query = d_in[0];
    const void* key   = d_in[1];
    const void* value = d_in[2];
    const void* Wq    = d_in[3];
    const void* bq    = d_in[4];
    const void* Wk    = d_in[5];
    const void* bk    = d_in[6];
    const void* Wv    = d_in[7];
    const void* bv    = d_in[8];

    char* w = (char*)d_ws;
    const size_t NE = (size_t)BB * HH * LL * DK;   // 4,194,304
    float* Kf  = (float*)w;  w += NE * 4;
    float* Vf  = (float*)w;  w += NE * 4;
    float* Qf  = (float*)w;  w += NE * 4;
    double* Mv = (double*)w; w += (size_t)BH * LL * 8;
    double* Kbar = (double*)w; w += (size_t)BH * DK * 8;
    int* sel   = (int*)w;    w += (size_t)BH * UU * 4;
    int* flag  = (int*)w;    w += 64;
    float* S    = (float*)w; w += (size_t)BH * UU * LL * 4;    // 10.49 MB
    float* part = (float*)w; w += (size_t)BH * 8 * UU * DK * 4; // 2.62 MB
    u16* Whi = (u16*)w;      w += (size_t)DD * DD * 2;          // 2.10 MB
    u16* Wlo = (u16*)w;      w += (size_t)DD * DD * 2;          // 2.10 MB
    float* M1 = (float*)w;   w += (size_t)BH * LL * 4;          // 0.26 MB
    float* M2 = (float*)w;   w += (size_t)BH * LL * 4;
    int* I1   = (int*)w;     w += (size_t)BH * LL * 4;
    int* alist = (int*)w;    w += (size_t)BH * LL * 4;
    int* cnt  = (int*)w;     w += 64;

    float* attnOut  = (float*)d_out;                       // FP32 outputs
    float* probsOut = attnOut + (size_t)BB * UU * DD;

    dim3 blk(256);
    detect_dtype_r17<<<1, blk, 0, stream>>>((const u16*)query, flag, cnt);
    preconvW_r16<<<1024, blk, 0, stream>>>(Wv, Whi, Wlo, flag);
    proj_f4_r13<<<dim3(32, 16, 2), blk, 0, stream>>>(key, query, Wk, Wq, bk, bq,
                                                     Kf, Qf, flag);
    proj_mfma_v_r16<<<dim3(64, 8), blk, 0, stream>>>(value, Whi, Wlo, bv, Vf, flag);
    kbar_r8<<<32, blk, 0, stream>>>(Kf, Kbar);
    statsq_r17<<<dim3(16, 32), blk, 0, stream>>>(Qf, Kf, M1, I1, M2);
    rescue_r17<<<256, blk, 0, stream>>>(Qf, Kf, Kbar, M1, I1, M2, Mv, alist, cnt);
    ambig_r17<<<128, blk, 0, stream>>>(Qf, Kf, Kbar, alist, cnt, Mv);
    topk_wave_r10<<<32, dim3(64), 0, stream>>>(Mv, sel);
    scores_r15<<<dim3(16, 32), blk, 0, stream>>>(Qf, Kf, sel, S);
    softmax_r12<<<dim3(UU, 32), blk, 0, stream>>>(S, probsOut);
    pv_r15<<<dim3(8, 32, 2), blk, 0, stream>>>(probsOut, Vf, part);
    pvred_r12<<<dim3(UU, 32), dim3(64), 0, stream>>>(part, attnOut);
}